// Round 8
// baseline (153.509 us; speedup 1.0000x reference)
//
#include <hip/hip_runtime.h>
#include <hip/hip_bf16.h>
#include <math.h>

#define Bn 4
#define Nn 512
#define Dn 128
#define Hn 64
#define TT 4096                  // table resolution (nearest-neighbor lookup)
#define EPB 8                    // table entries per k0 block
#define K0B ((TT + 1 + EPB - 1) / EPB)

__device__ __forceinline__ float silu_f(float x) {
    return x * (1.0f / (1.0f + __expf(-x)));
}

// ---------------------------------------------------------------------------
// k0: tabulate radial MLP G(x): scalar -> R^128 at x = e/TT, e = 0..TT.
// 513 blocks x 256 threads; weights staged in LDS; 8 entries/block
// (4 concurrent across waves x 2 rounds).  (R7-verified structure)
// ---------------------------------------------------------------------------
struct K0S {
    float rW2s[Hn][Hn];
    float rW3s[Hn][Dn];
    float rW1s[Hn], rb1s[Hn], rg1s[Hn], rb2s[Hn], rg2s[Hn];
    float rb3s[Dn];
    float h1buf[4][Hn];
    float h2buf[4][Hn];
};

__global__ __launch_bounds__(256)
void k0_build_table(const float* __restrict__ rW1, const float* __restrict__ rb1,
                    const float* __restrict__ rg1,
                    const float* __restrict__ rW2, const float* __restrict__ rb2,
                    const float* __restrict__ rg2,
                    const float* __restrict__ rW3, const float* __restrict__ rb3,
                    __hip_bfloat16* __restrict__ table)
{
    __shared__ K0S sm;
    const int t   = threadIdx.x;
    const int k   = t & 63;
    const int wv  = t >> 6;
    const int blk = blockIdx.x;

    #pragma unroll
    for (int idx = t; idx < Hn * Hn; idx += 256)
        sm.rW2s[idx >> 6][idx & 63] = rW2[idx];
    #pragma unroll
    for (int idx = t; idx < Hn * Dn; idx += 256)
        sm.rW3s[idx >> 7][idx & 127] = rW3[idx];
    if (t < Hn) {
        sm.rW1s[t] = rW1[t];
        sm.rb1s[t] = rb1[t];
        sm.rg1s[t] = rg1[t];
        sm.rb2s[t] = rb2[t];
        sm.rg2s[t] = rg2[t];
    }
    if (t < Dn) sm.rb3s[t] = rb3[t];
    __syncthreads();

    for (int r = 0; r < 2; ++r) {
        const int e = blk * EPB + r * 4 + wv;
        const float x = (float)e * (1.0f / (float)TT);

        float h = silu_f(x * sm.rW1s[k] + sm.rb1s[k]);
        float s1 = h, s2 = h * h;
        #pragma unroll
        for (int m = 1; m < 64; m <<= 1) { s1 += __shfl_xor(s1, m); s2 += __shfl_xor(s2, m); }
        float mean = s1 * (1.0f / 64.0f);
        float var  = s2 * (1.0f / 64.0f) - mean * mean;
        float rs   = rsqrtf(var + 1e-5f);
        sm.h1buf[wv][k] = (h - mean) * rs * sm.rg1s[k];
        __syncthreads();

        float p = 0.f;
        #pragma unroll 8
        for (int kk = 0; kk < Hn; ++kk) p += sm.h1buf[wv][kk] * sm.rW2s[kk][k];
        float h2 = silu_f(p + sm.rb2s[k]);
        s1 = h2; s2 = h2 * h2;
        #pragma unroll
        for (int m = 1; m < 64; m <<= 1) { s1 += __shfl_xor(s1, m); s2 += __shfl_xor(s2, m); }
        mean = s1 * (1.0f / 64.0f);
        var  = s2 * (1.0f / 64.0f) - mean * mean;
        rs   = rsqrtf(var + 1e-5f);
        sm.h2buf[wv][k] = (h2 - mean) * rs * sm.rg2s[k];
        __syncthreads();

        #pragma unroll
        for (int dd = 0; dd < 2; ++dd) {
            const int d = dd * 64 + k;
            float f = sm.rb3s[d];
            #pragma unroll 8
            for (int kk = 0; kk < Hn; ++kk) f += sm.h2buf[wv][kk] * sm.rW3s[kk][d];
            if (e <= TT) table[e * Dn + d] = __float2bfloat16(f);
        }
        __syncthreads();
    }
}

// ---------------------------------------------------------------------------
// k1: fused contraction + node MLP.  Block per (b,i), 256 threads.
//   - full ntab staged in LDS as bf16 (100x128 = 25.6 KB), converted from
//     the f32 global in-kernel (cuts 512B/entry of global traffic)
//   - nearest-neighbor table lookup (1 row = 256B/entry instead of 2)
//   - R7-verified ballot compaction (deterministic, no atomics)
//   - R4/R6-verified node-MLP epilogue
// ---------------------------------------------------------------------------
struct K1S {
    __hip_bfloat162 ntabS[100 * 64];   // [atom][d-pair] packed bf16x2 (25.6 KB)
    float  wE[528];
    int    metaE[528];                 // e | atom<<16
    int    wcnt[4];
    float  accs[4][64][2];
    float  xs[256];
    float  r1[2], r2[2];
    float  x2[128];
};

__global__ __launch_bounds__(256)
void k1_fused(const int* __restrict__ atoms, const float* __restrict__ rel,
              const int* __restrict__ adj, const int* __restrict__ mask,
              const float* __restrict__ soft, const float* __restrict__ ntab,
              const __hip_bfloat16* __restrict__ table,
              const float* __restrict__ atom_tab,
              const float* __restrict__ nW1, const float* __restrict__ nb1,
              const float* __restrict__ ng,
              const float* __restrict__ nW2, const float* __restrict__ nb2,
              float* __restrict__ out)
{
    __shared__ K1S sm;
    const int t    = threadIdx.x;
    const int lane = t & 63;
    const int wv   = t >> 6;
    const int bi   = blockIdx.x;        // b*N + i
    const int b    = bi >> 9;
    const int i    = bi & 511;
    const int rowbase = bi * Nn;

    // ---- stage ntab -> LDS bf16 (coalesced float2 reads) ----
    for (int idx = t; idx < 100 * 64; idx += 256) {
        const float2 fv = ((const float2*)ntab)[idx];
        sm.ntabS[idx] = __hip_bfloat162(__float2bfloat16(fv.x), __float2bfloat16(fv.y));
    }

    // ---- stage + deterministic ballot compaction (2 rounds of 256 j) ----
    int total = 0;
    for (int it = 0; it < 2; ++it) {
        const int j = it * 256 + t;
        const float dist = rel[rowbase + j];
        const int   adjv = adj[rowbase + j];
        const int   mk   = mask[b * Nn + j];
        const float w = (adjv != 0 && mk != 0 && j != i) ? soft[rowbase + j] : 0.0f;
        int e = (int)(dist * (float)TT + 0.5f);     // nearest table entry
        e = min(max(e, 0), TT);

        const bool act = (w != 0.0f);
        const unsigned long long bm = __ballot(act);
        const int before = __popcll(bm & ((1ull << lane) - 1ull));
        if (lane == 0) sm.wcnt[wv] = (int)__popcll(bm);
        __syncthreads();
        int base = total;
        for (int q = 0; q < 4; ++q) {
            if (q < wv) base += sm.wcnt[q];
            total += sm.wcnt[q];
        }
        if (act) {
            const int pos = base + before;
            sm.wE[pos]    = w;
            sm.metaE[pos] = e | (atoms[b * Nn + j] << 16);
        }
        __syncthreads();
    }

    // pad entry list to multiple of 16
    const int cnt  = total;
    const int cntP = (cnt + 15) & ~15;
    if (t < cntP - cnt) {
        sm.wE[cnt + t]    = 0.0f;
        sm.metaE[cnt + t] = 0;
    }
    __syncthreads();

    // ---- branch-free compacted contraction ----
    const int d0 = lane * 2;
    float a0 = 0.f, a1 = 0.f;
    const int trips = cntP >> 2;
    #pragma unroll 4
    for (int n = 0; n < trips; ++n) {
        const int en  = wv + (n << 2);
        const float w   = sm.wE[en];            // broadcast
        const int  meta = sm.metaE[en];
        const int  e    = meta & 0xFFFF;
        const int  at   = meta >> 16;
        const __hip_bfloat162 tv2 = *(const __hip_bfloat162*)&table[e * Dn + d0];
        const __hip_bfloat162 nv2 = sm.ntabS[at * 64 + lane];   // conflict-free
        const float2 tv = __bfloat1622float2(tv2);
        const float2 nv = __bfloat1622float2(nv2);
        a0 += (w * nv.x) * tv.x;
        a1 += (w * nv.y) * tv.y;
    }
    sm.accs[wv][lane][0] = a0;
    sm.accs[wv][lane][1] = a1;
    __syncthreads();

    // ---- fused node-MLP epilogue (R4/R6-verified logic) ----
    const int a = atoms[bi];
    if (t < Dn) {
        float r = 0.f;
        #pragma unroll
        for (int q = 0; q < 4; ++q) r += sm.accs[q][t >> 1][t & 1];
        sm.xs[t]       = atom_tab[a * Dn + t];
        sm.xs[128 + t] = r;
    }
    __syncthreads();

    float s = 0.f;
    if (t < Dn) {
        float p0 = 0.f, p1 = 0.f, p2 = 0.f, p3 = 0.f;
        #pragma unroll 4
        for (int c = 0; c < 256; c += 4) {
            p0 += sm.xs[c + 0] * nW1[(c + 0) * Dn + t];
            p1 += sm.xs[c + 1] * nW1[(c + 1) * Dn + t];
            p2 += sm.xs[c + 2] * nW1[(c + 2) * Dn + t];
            p3 += sm.xs[c + 3] * nW1[(c + 3) * Dn + t];
        }
        s = (p0 + p1) + (p2 + p3) + nb1[t];
        float a1r = s, a2r = s * s;
        #pragma unroll
        for (int off = 32; off > 0; off >>= 1) {
            a1r += __shfl_down(a1r, off);
            a2r += __shfl_down(a2r, off);
        }
        if ((t & 63) == 0) { sm.r1[t >> 6] = a1r; sm.r2[t >> 6] = a2r; }
    }
    __syncthreads();

    if (t < Dn) {
        const float S1 = sm.r1[0] + sm.r1[1];
        const float S2 = sm.r2[0] + sm.r2[1];
        const float m  = S1 * (1.0f / 128.0f);
        const float vr = S2 * (1.0f / 128.0f) - m * m;
        const float rs = rsqrtf(vr + 1e-5f);
        sm.x2[t] = silu_f((s - m) * rs * ng[t]);   // LN first, THEN silu
    }
    __syncthreads();

    if (t < Dn) {
        float q0 = 0.f, q1 = 0.f, q2 = 0.f, q3 = 0.f;
        #pragma unroll 4
        for (int c = 0; c < 128; c += 4) {
            q0 += sm.x2[c + 0] * nW2[(c + 0) * Dn + t];
            q1 += sm.x2[c + 1] * nW2[(c + 1) * Dn + t];
            q2 += sm.x2[c + 2] * nW2[(c + 2) * Dn + t];
            q3 += sm.x2[c + 3] * nW2[(c + 3) * Dn + t];
        }
        out[bi * Dn + t] = (q0 + q1) + (q2 + q3) + nb2[t];
    }
}

// ---------------------------------------------------------------------------
extern "C" void kernel_launch(void* const* d_in, const int* in_sizes, int n_in,
                              void* d_out, int out_size, void* d_ws, size_t ws_size,
                              hipStream_t stream)
{
    (void)in_sizes; (void)n_in; (void)out_size; (void)ws_size;

    const int*   atoms = (const int*)d_in[0];
    const float* rel   = (const float*)d_in[1];
    const int*   adj   = (const int*)d_in[2];
    const int*   mask  = (const int*)d_in[3];
    const float* soft  = (const float*)d_in[4];
    const float* atab  = (const float*)d_in[5];
    const float* ntab  = (const float*)d_in[6];
    const float* rW1   = (const float*)d_in[7];
    const float* rb1   = (const float*)d_in[8];
    const float* rg1   = (const float*)d_in[9];
    const float* rW2   = (const float*)d_in[10];
    const float* rb2   = (const float*)d_in[11];
    const float* rg2   = (const float*)d_in[12];
    const float* rW3   = (const float*)d_in[13];
    const float* rb3   = (const float*)d_in[14];
    const float* nW1   = (const float*)d_in[15];
    const float* nb1   = (const float*)d_in[16];
    const float* ng    = (const float*)d_in[17];
    const float* nW2   = (const float*)d_in[18];
    const float* nb2   = (const float*)d_in[19];

    __hip_bfloat16* table = (__hip_bfloat16*)d_ws;   // (TT+1) x 128 bf16 ~ 1 MB
    float* out = (float*)d_out;

    hipLaunchKernelGGL(k0_build_table, dim3(K0B), dim3(256), 0, stream,
                       rW1, rb1, rg1, rW2, rb2, rg2, rW3, rb3, table);
    hipLaunchKernelGGL(k1_fused, dim3(Bn * Nn), dim3(256), 0, stream,
                       atoms, rel, adj, mask, soft, ntab, table,
                       atab, nW1, nb1, ng, nW2, nb2, out);
}

// Round 9
// 147.139 us; speedup vs baseline: 1.0433x; 1.0433x over previous
//
#include <hip/hip_runtime.h>
#include <hip/hip_bf16.h>
#include <math.h>

#define Bn 4
#define Nn 512
#define Dn 128
#define Hn 64
#define TT 4096                  // table resolution (nearest-neighbor lookup)
#define EPB 8
#define K0B ((TT + 1 + EPB - 1) / EPB)

__device__ __forceinline__ float silu_f(float x) {
    return x * (1.0f / (1.0f + __expf(-x)));
}

// ---------------------------------------------------------------------------
// k0: tabulate radial MLP G(x): scalar -> R^128 at x = e/TT (R7/R8-verified).
// ---------------------------------------------------------------------------
struct K0S {
    float rW2s[Hn][Hn];
    float rW3s[Hn][Dn];
    float rW1s[Hn], rb1s[Hn], rg1s[Hn], rb2s[Hn], rg2s[Hn];
    float rb3s[Dn];
    float h1buf[4][Hn];
    float h2buf[4][Hn];
};

__global__ __launch_bounds__(256)
void k0_build_table(const float* __restrict__ rW1, const float* __restrict__ rb1,
                    const float* __restrict__ rg1,
                    const float* __restrict__ rW2, const float* __restrict__ rb2,
                    const float* __restrict__ rg2,
                    const float* __restrict__ rW3, const float* __restrict__ rb3,
                    __hip_bfloat16* __restrict__ table)
{
    __shared__ K0S sm;
    const int t   = threadIdx.x;
    const int k   = t & 63;
    const int wv  = t >> 6;
    const int blk = blockIdx.x;

    #pragma unroll
    for (int idx = t; idx < Hn * Hn; idx += 256)
        sm.rW2s[idx >> 6][idx & 63] = rW2[idx];
    #pragma unroll
    for (int idx = t; idx < Hn * Dn; idx += 256)
        sm.rW3s[idx >> 7][idx & 127] = rW3[idx];
    if (t < Hn) {
        sm.rW1s[t] = rW1[t];
        sm.rb1s[t] = rb1[t];
        sm.rg1s[t] = rg1[t];
        sm.rb2s[t] = rb2[t];
        sm.rg2s[t] = rg2[t];
    }
    if (t < Dn) sm.rb3s[t] = rb3[t];
    __syncthreads();

    for (int r = 0; r < 2; ++r) {
        const int e = blk * EPB + r * 4 + wv;
        const float x = (float)e * (1.0f / (float)TT);

        float h = silu_f(x * sm.rW1s[k] + sm.rb1s[k]);
        float s1 = h, s2 = h * h;
        #pragma unroll
        for (int m = 1; m < 64; m <<= 1) { s1 += __shfl_xor(s1, m); s2 += __shfl_xor(s2, m); }
        float mean = s1 * (1.0f / 64.0f);
        float var  = s2 * (1.0f / 64.0f) - mean * mean;
        float rs   = rsqrtf(var + 1e-5f);
        sm.h1buf[wv][k] = (h - mean) * rs * sm.rg1s[k];
        __syncthreads();

        float p = 0.f;
        #pragma unroll 8
        for (int kk = 0; kk < Hn; ++kk) p += sm.h1buf[wv][kk] * sm.rW2s[kk][k];
        float h2 = silu_f(p + sm.rb2s[k]);
        s1 = h2; s2 = h2 * h2;
        #pragma unroll
        for (int m = 1; m < 64; m <<= 1) { s1 += __shfl_xor(s1, m); s2 += __shfl_xor(s2, m); }
        mean = s1 * (1.0f / 64.0f);
        var  = s2 * (1.0f / 64.0f) - mean * mean;
        rs   = rsqrtf(var + 1e-5f);
        sm.h2buf[wv][k] = (h2 - mean) * rs * sm.rg2s[k];
        __syncthreads();

        #pragma unroll
        for (int dd = 0; dd < 2; ++dd) {
            const int d = dd * 64 + k;
            float f = sm.rb3s[d];
            #pragma unroll 8
            for (int kk = 0; kk < Hn; ++kk) f += sm.h2buf[wv][kk] * sm.rW3s[kk][d];
            if (e <= TT) table[e * Dn + d] = __float2bfloat16(f);
        }
        __syncthreads();
    }
}

// ---------------------------------------------------------------------------
// k1: fused contraction + node MLP.  Block per (b,i), 256 threads.
//   - ntab in LDS bf16 (R8-verified staging)
//   - single-barrier double ballot compaction; (w,meta) fused to float2
//   - wave owns a contiguous entry quarter, unroll 8 (8 loads in flight)
//   - epilogue GEMVs split across all 256 threads (half c-range each)
// ---------------------------------------------------------------------------
struct K1S {
    __hip_bfloat162 ntabS[100 * 64];   // 25.6 KB
    float2 entE[544];                  // (w, asfloat(e | atom<<16))
    int    wcnt[4][2];
    float  accs[4][64][2];
    float  xs[256];
    float  p1[2][128];
    float  r1[2], r2[2];
    float  x2[128];
};

__global__ __launch_bounds__(256)
void k1_fused(const int* __restrict__ atoms, const float* __restrict__ rel,
              const int* __restrict__ adj, const int* __restrict__ mask,
              const float* __restrict__ soft, const float* __restrict__ ntab,
              const __hip_bfloat16* __restrict__ table,
              const float* __restrict__ atom_tab,
              const float* __restrict__ nW1, const float* __restrict__ nb1,
              const float* __restrict__ ng,
              const float* __restrict__ nW2, const float* __restrict__ nb2,
              float* __restrict__ out)
{
    __shared__ K1S sm;
    const int t    = threadIdx.x;
    const int lane = t & 63;
    const int wv   = t >> 6;
    const int bi   = blockIdx.x;        // b*N + i
    const int b    = bi >> 9;
    const int i    = bi & 511;
    const int rowbase = bi * Nn;

    // ---- stage ntab -> LDS bf16 (coalesced float2 reads) ----
    for (int idx = t; idx < 100 * 64; idx += 256) {
        const float2 fv = ((const float2*)ntab)[idx];
        sm.ntabS[idx] = __hip_bfloat162(__float2bfloat16(fv.x), __float2bfloat16(fv.y));
    }

    // ---- double ballot, single barrier ----
    const int j0 = t, j1 = t + 256;
    const float d0v = rel[rowbase + j0];
    const float d1v = rel[rowbase + j1];
    const int   a0v = adj[rowbase + j0];
    const int   a1v = adj[rowbase + j1];
    const int   m0v = mask[b * Nn + j0];
    const int   m1v = mask[b * Nn + j1];
    const float w0 = (a0v != 0 && m0v != 0 && j0 != i) ? soft[rowbase + j0] : 0.0f;
    const float w1 = (a1v != 0 && m1v != 0 && j1 != i) ? soft[rowbase + j1] : 0.0f;
    int e0 = (int)(d0v * (float)TT + 0.5f); e0 = min(max(e0, 0), TT);
    int e1 = (int)(d1v * (float)TT + 0.5f); e1 = min(max(e1, 0), TT);

    const bool act0 = (w0 != 0.0f), act1 = (w1 != 0.0f);
    const unsigned long long bm0 = __ballot(act0);
    const unsigned long long bm1 = __ballot(act1);
    const unsigned long long below = (1ull << lane) - 1ull;
    const int bef0 = __popcll(bm0 & below);
    const int bef1 = __popcll(bm1 & below);
    if (lane == 0) { sm.wcnt[wv][0] = (int)__popcll(bm0); sm.wcnt[wv][1] = (int)__popcll(bm1); }
    __syncthreads();

    int base0 = 0, total0 = 0, base1 = 0, total1 = 0;
    #pragma unroll
    for (int q = 0; q < 4; ++q) {
        if (q < wv) { base0 += sm.wcnt[q][0]; base1 += sm.wcnt[q][1]; }
        total0 += sm.wcnt[q][0];
        total1 += sm.wcnt[q][1];
    }
    if (act0) sm.entE[base0 + bef0] =
        make_float2(w0, __int_as_float(e0 | (atoms[b * Nn + j0] << 16)));
    if (act1) sm.entE[total0 + base1 + bef1] =
        make_float2(w1, __int_as_float(e1 | (atoms[b * Nn + j1] << 16)));

    const int cnt  = total0 + total1;
    const int cntP = (cnt + 31) & ~31;           // multiple of 32 = 8/wave granule
    if (t < cntP - cnt) sm.entE[cnt + t] = make_float2(0.0f, __int_as_float(0));
    __syncthreads();

    // ---- contraction: wave owns contiguous quarter, unroll 8 ----
    const int dd0 = lane * 2;
    const int quarter = cntP >> 2;
    const int ebase   = wv * quarter;
    float a0 = 0.f, a1 = 0.f;
    #pragma unroll 8
    for (int n = 0; n < quarter; ++n) {
        const float2 E  = sm.entE[ebase + n];    // one ds_read_b64, broadcast
        const float w   = E.x;
        const int  meta = __float_as_int(E.y);
        const int  e    = meta & 0xFFFF;
        const int  at   = meta >> 16;
        const __hip_bfloat162 tv2 = *(const __hip_bfloat162*)&table[e * Dn + dd0];
        const __hip_bfloat162 nv2 = sm.ntabS[at * 64 + lane];
        const float2 tv = __bfloat1622float2(tv2);
        const float2 nv = __bfloat1622float2(nv2);
        a0 += (w * nv.x) * tv.x;
        a1 += (w * nv.y) * tv.y;
    }
    sm.accs[wv][lane][0] = a0;
    sm.accs[wv][lane][1] = a1;
    __syncthreads();

    // ---- fused node-MLP epilogue, GEMVs split across all 256 threads ----
    const int a = atoms[bi];
    if (t < Dn) {
        float r = 0.f;
        #pragma unroll
        for (int q = 0; q < 4; ++q) r += sm.accs[q][t >> 1][t & 1];
        sm.xs[t]       = atom_tab[a * Dn + t];
        sm.xs[128 + t] = r;
    }
    __syncthreads();

    // GEMV1: thread (to = t&127, ch = t>>7) does c in [ch*128, ch*128+128)
    {
        const int to = t & 127, ch = t >> 7;
        const int c0 = ch * 128;
        float p0 = 0.f, p1v = 0.f, p2 = 0.f, p3 = 0.f;
        #pragma unroll 4
        for (int c = 0; c < 128; c += 4) {
            p0  += sm.xs[c0 + c + 0] * nW1[(c0 + c + 0) * Dn + to];
            p1v += sm.xs[c0 + c + 1] * nW1[(c0 + c + 1) * Dn + to];
            p2  += sm.xs[c0 + c + 2] * nW1[(c0 + c + 2) * Dn + to];
            p3  += sm.xs[c0 + c + 3] * nW1[(c0 + c + 3) * Dn + to];
        }
        sm.p1[ch][to] = (p0 + p1v) + (p2 + p3);
    }
    __syncthreads();

    float s = 0.f;
    if (t < Dn) {
        s = sm.p1[0][t] + sm.p1[1][t] + nb1[t];
        float a1r = s, a2r = s * s;
        #pragma unroll
        for (int off = 32; off > 0; off >>= 1) {
            a1r += __shfl_down(a1r, off);
            a2r += __shfl_down(a2r, off);
        }
        if ((t & 63) == 0) { sm.r1[t >> 6] = a1r; sm.r2[t >> 6] = a2r; }
    }
    __syncthreads();

    if (t < Dn) {
        const float S1 = sm.r1[0] + sm.r1[1];
        const float S2 = sm.r2[0] + sm.r2[1];
        const float m  = S1 * (1.0f / 128.0f);
        const float vr = S2 * (1.0f / 128.0f) - m * m;
        const float rs = rsqrtf(vr + 1e-5f);
        sm.x2[t] = silu_f((s - m) * rs * ng[t]);   // LN first, THEN silu
    }
    __syncthreads();

    // GEMV2: thread (to, ch) does c in [ch*64, ch*64+64)
    {
        const int to = t & 127, ch = t >> 7;
        const int c0 = ch * 64;
        float q0 = 0.f, q1 = 0.f, q2 = 0.f, q3 = 0.f;
        #pragma unroll 4
        for (int c = 0; c < 64; c += 4) {
            q0 += sm.x2[c0 + c + 0] * nW2[(c0 + c + 0) * Dn + to];
            q1 += sm.x2[c0 + c + 1] * nW2[(c0 + c + 1) * Dn + to];
            q2 += sm.x2[c0 + c + 2] * nW2[(c0 + c + 2) * Dn + to];
            q3 += sm.x2[c0 + c + 3] * nW2[(c0 + c + 3) * Dn + to];
        }
        sm.p1[ch][to] = (q0 + q1) + (q2 + q3);   // reuse p1
    }
    __syncthreads();

    if (t < Dn) {
        out[bi * Dn + t] = sm.p1[0][t] + sm.p1[1][t] + nb2[t];
    }
}

// ---------------------------------------------------------------------------
extern "C" void kernel_launch(void* const* d_in, const int* in_sizes, int n_in,
                              void* d_out, int out_size, void* d_ws, size_t ws_size,
                              hipStream_t stream)
{
    (void)in_sizes; (void)n_in; (void)out_size; (void)ws_size;

    const int*   atoms = (const int*)d_in[0];
    const float* rel   = (const float*)d_in[1];
    const int*   adj   = (const int*)d_in[2];
    const int*   mask  = (const int*)d_in[3];
    const float* soft  = (const float*)d_in[4];
    const float* atab  = (const float*)d_in[5];
    const float* ntab  = (const float*)d_in[6];
    const float* rW1   = (const float*)d_in[7];
    const float* rb1   = (const float*)d_in[8];
    const float* rg1   = (const float*)d_in[9];
    const float* rW2   = (const float*)d_in[10];
    const float* rb2   = (const float*)d_in[11];
    const float* rg2   = (const float*)d_in[12];
    const float* rW3   = (const float*)d_in[13];
    const float* rb3   = (const float*)d_in[14];
    const float* nW1   = (const float*)d_in[15];
    const float* nb1   = (const float*)d_in[16];
    const float* ng    = (const float*)d_in[17];
    const float* nW2   = (const float*)d_in[18];
    const float* nb2   = (const float*)d_in[19];

    __hip_bfloat16* table = (__hip_bfloat16*)d_ws;   // (TT+1) x 128 bf16 ~ 1 MB
    float* out = (float*)d_out;

    hipLaunchKernelGGL(k0_build_table, dim3(K0B), dim3(256), 0, stream,
                       rW1, rb1, rg1, rW2, rb2, rg2, rW3, rb3, table);
    hipLaunchKernelGGL(k1_fused, dim3(Bn * Nn), dim3(256), 0, stream,
                       atoms, rel, adj, mask, soft, ntab, table,
                       atab, nW1, nb1, ng, nW2, nb2, out);
}

// Round 10
// 146.236 us; speedup vs baseline: 1.0497x; 1.0062x over previous
//
#include <hip/hip_runtime.h>
#include <hip/hip_bf16.h>
#include <math.h>

#define Bn 4
#define Nn 512
#define Dn 128
#define Hn 64
#define TT 4096                  // table resolution (nearest-neighbor lookup)
#define EPB 8
#define K0B ((TT + 1 + EPB - 1) / EPB)

__device__ __forceinline__ float silu_f(float x) {
    return x * (1.0f / (1.0f + __expf(-x)));
}

// ---------------------------------------------------------------------------
// k0: tabulate radial MLP G(x): scalar -> R^128 at x = e/TT (R7/R8-verified).
// ---------------------------------------------------------------------------
struct K0S {
    float rW2s[Hn][Hn];
    float rW3s[Hn][Dn];
    float rW1s[Hn], rb1s[Hn], rg1s[Hn], rb2s[Hn], rg2s[Hn];
    float rb3s[Dn];
    float h1buf[4][Hn];
    float h2buf[4][Hn];
};

__global__ __launch_bounds__(256)
void k0_build_table(const float* __restrict__ rW1, const float* __restrict__ rb1,
                    const float* __restrict__ rg1,
                    const float* __restrict__ rW2, const float* __restrict__ rb2,
                    const float* __restrict__ rg2,
                    const float* __restrict__ rW3, const float* __restrict__ rb3,
                    __hip_bfloat16* __restrict__ table)
{
    __shared__ K0S sm;
    const int t   = threadIdx.x;
    const int k   = t & 63;
    const int wv  = t >> 6;
    const int blk = blockIdx.x;

    #pragma unroll
    for (int idx = t; idx < Hn * Hn; idx += 256)
        sm.rW2s[idx >> 6][idx & 63] = rW2[idx];
    #pragma unroll
    for (int idx = t; idx < Hn * Dn; idx += 256)
        sm.rW3s[idx >> 7][idx & 127] = rW3[idx];
    if (t < Hn) {
        sm.rW1s[t] = rW1[t];
        sm.rb1s[t] = rb1[t];
        sm.rg1s[t] = rg1[t];
        sm.rb2s[t] = rb2[t];
        sm.rg2s[t] = rg2[t];
    }
    if (t < Dn) sm.rb3s[t] = rb3[t];
    __syncthreads();

    for (int r = 0; r < 2; ++r) {
        const int e = blk * EPB + r * 4 + wv;
        const float x = (float)e * (1.0f / (float)TT);

        float h = silu_f(x * sm.rW1s[k] + sm.rb1s[k]);
        float s1 = h, s2 = h * h;
        #pragma unroll
        for (int m = 1; m < 64; m <<= 1) { s1 += __shfl_xor(s1, m); s2 += __shfl_xor(s2, m); }
        float mean = s1 * (1.0f / 64.0f);
        float var  = s2 * (1.0f / 64.0f) - mean * mean;
        float rs   = rsqrtf(var + 1e-5f);
        sm.h1buf[wv][k] = (h - mean) * rs * sm.rg1s[k];
        __syncthreads();

        float p = 0.f;
        #pragma unroll 8
        for (int kk = 0; kk < Hn; ++kk) p += sm.h1buf[wv][kk] * sm.rW2s[kk][k];
        float h2 = silu_f(p + sm.rb2s[k]);
        s1 = h2; s2 = h2 * h2;
        #pragma unroll
        for (int m = 1; m < 64; m <<= 1) { s1 += __shfl_xor(s1, m); s2 += __shfl_xor(s2, m); }
        mean = s1 * (1.0f / 64.0f);
        var  = s2 * (1.0f / 64.0f) - mean * mean;
        rs   = rsqrtf(var + 1e-5f);
        sm.h2buf[wv][k] = (h2 - mean) * rs * sm.rg2s[k];
        __syncthreads();

        #pragma unroll
        for (int dd = 0; dd < 2; ++dd) {
            const int d = dd * 64 + k;
            float f = sm.rb3s[d];
            #pragma unroll 8
            for (int kk = 0; kk < Hn; ++kk) f += sm.h2buf[wv][kk] * sm.rW3s[kk][d];
            if (e <= TT) table[e * Dn + d] = __float2bfloat16(f);
        }
        __syncthreads();
    }
}

// ---------------------------------------------------------------------------
// k1: fused contraction + node MLP.  Block per (b,i), 256 threads.
//   - ntab in LDS bf16 (R8-verified); single-barrier double ballot (R9)
//   - wave owns a contiguous entry quarter, unroll 8 (R9)
//   - epilogue GEMVs: og = t&31 owns 4 outputs (float4 weight loads),
//     ch = t>>5 owns 1/8 of the c-reduction; partials via 4KB LDS tile.
//     (R9 had 128 scalar stride-512B loads/thread -> latency-serial.)
// ---------------------------------------------------------------------------
struct K1S {
    __hip_bfloat162 ntabS[100 * 64];   // 25.6 KB
    float2 entE[544];                  // (w, asfloat(e | atom<<16))
    int    wcnt[4][2];
    float  accs[4][64][2];
    float  xs[256];
    float  pp[8][128];                 // GEMV partials
    float  r1[2], r2[2];
    float  x2[128];
};

__global__ __launch_bounds__(256)
void k1_fused(const int* __restrict__ atoms, const float* __restrict__ rel,
              const int* __restrict__ adj, const int* __restrict__ mask,
              const float* __restrict__ soft, const float* __restrict__ ntab,
              const __hip_bfloat16* __restrict__ table,
              const float* __restrict__ atom_tab,
              const float* __restrict__ nW1, const float* __restrict__ nb1,
              const float* __restrict__ ng,
              const float* __restrict__ nW2, const float* __restrict__ nb2,
              float* __restrict__ out)
{
    __shared__ K1S sm;
    const int t    = threadIdx.x;
    const int lane = t & 63;
    const int wv   = t >> 6;
    const int bi   = blockIdx.x;        // b*N + i
    const int b    = bi >> 9;
    const int i    = bi & 511;
    const int rowbase = bi * Nn;

    // ---- stage ntab -> LDS bf16 (coalesced float2 reads) ----
    for (int idx = t; idx < 100 * 64; idx += 256) {
        const float2 fv = ((const float2*)ntab)[idx];
        sm.ntabS[idx] = __hip_bfloat162(__float2bfloat16(fv.x), __float2bfloat16(fv.y));
    }

    // ---- double ballot, single barrier (R9-verified) ----
    const int j0 = t, j1 = t + 256;
    const float d0v = rel[rowbase + j0];
    const float d1v = rel[rowbase + j1];
    const int   a0v = adj[rowbase + j0];
    const int   a1v = adj[rowbase + j1];
    const int   m0v = mask[b * Nn + j0];
    const int   m1v = mask[b * Nn + j1];
    const float w0 = (a0v != 0 && m0v != 0 && j0 != i) ? soft[rowbase + j0] : 0.0f;
    const float w1 = (a1v != 0 && m1v != 0 && j1 != i) ? soft[rowbase + j1] : 0.0f;
    int e0 = (int)(d0v * (float)TT + 0.5f); e0 = min(max(e0, 0), TT);
    int e1 = (int)(d1v * (float)TT + 0.5f); e1 = min(max(e1, 0), TT);

    const bool act0 = (w0 != 0.0f), act1 = (w1 != 0.0f);
    const unsigned long long bm0 = __ballot(act0);
    const unsigned long long bm1 = __ballot(act1);
    const unsigned long long below = (1ull << lane) - 1ull;
    const int bef0 = __popcll(bm0 & below);
    const int bef1 = __popcll(bm1 & below);
    if (lane == 0) { sm.wcnt[wv][0] = (int)__popcll(bm0); sm.wcnt[wv][1] = (int)__popcll(bm1); }
    __syncthreads();

    int base0 = 0, total0 = 0, base1 = 0, total1 = 0;
    #pragma unroll
    for (int q = 0; q < 4; ++q) {
        if (q < wv) { base0 += sm.wcnt[q][0]; base1 += sm.wcnt[q][1]; }
        total0 += sm.wcnt[q][0];
        total1 += sm.wcnt[q][1];
    }
    if (act0) sm.entE[base0 + bef0] =
        make_float2(w0, __int_as_float(e0 | (atoms[b * Nn + j0] << 16)));
    if (act1) sm.entE[total0 + base1 + bef1] =
        make_float2(w1, __int_as_float(e1 | (atoms[b * Nn + j1] << 16)));

    const int cnt  = total0 + total1;
    const int cntP = (cnt + 31) & ~31;
    if (t < cntP - cnt) sm.entE[cnt + t] = make_float2(0.0f, __int_as_float(0));
    __syncthreads();

    // ---- contraction: wave owns contiguous quarter, unroll 8 (R9) ----
    const int dd0 = lane * 2;
    const int quarter = cntP >> 2;
    const int ebase   = wv * quarter;
    float a0 = 0.f, a1 = 0.f;
    #pragma unroll 8
    for (int n = 0; n < quarter; ++n) {
        const float2 E  = sm.entE[ebase + n];
        const float w   = E.x;
        const int  meta = __float_as_int(E.y);
        const int  e    = meta & 0xFFFF;
        const int  at   = meta >> 16;
        const __hip_bfloat162 tv2 = *(const __hip_bfloat162*)&table[e * Dn + dd0];
        const __hip_bfloat162 nv2 = sm.ntabS[at * 64 + lane];
        const float2 tv = __bfloat1622float2(tv2);
        const float2 nv = __bfloat1622float2(nv2);
        a0 += (w * nv.x) * tv.x;
        a1 += (w * nv.y) * tv.y;
    }
    sm.accs[wv][lane][0] = a0;
    sm.accs[wv][lane][1] = a1;
    __syncthreads();

    // ---- fused node-MLP epilogue, float4 weight loads ----
    const int a = atoms[bi];
    if (t < Dn) {
        float r = 0.f;
        #pragma unroll
        for (int q = 0; q < 4; ++q) r += sm.accs[q][t >> 1][t & 1];
        sm.xs[t]       = atom_tab[a * Dn + t];
        sm.xs[128 + t] = r;
    }
    __syncthreads();

    const int og = t & 31;       // output group: outputs 4*og..4*og+3
    const int ch = t >> 5;       // c-chunk 0..7

    // GEMV1: c in [ch*32, ch*32+32)
    {
        const int c0 = ch * 32;
        float q0 = 0.f, q1 = 0.f, q2 = 0.f, q3 = 0.f;
        #pragma unroll 8
        for (int c = 0; c < 32; ++c) {
            const float  xv = sm.xs[c0 + c];
            const float4 wv4 = *(const float4*)&nW1[(c0 + c) * Dn + og * 4];
            q0 += xv * wv4.x; q1 += xv * wv4.y; q2 += xv * wv4.z; q3 += xv * wv4.w;
        }
        *(float4*)&sm.pp[ch][og * 4] = make_float4(q0, q1, q2, q3);
    }
    __syncthreads();

    float s = 0.f;
    if (t < Dn) {
        s = nb1[t];
        #pragma unroll
        for (int cc = 0; cc < 8; ++cc) s += sm.pp[cc][t];
        float a1r = s, a2r = s * s;
        #pragma unroll
        for (int off = 32; off > 0; off >>= 1) {
            a1r += __shfl_down(a1r, off);
            a2r += __shfl_down(a2r, off);
        }
        if ((t & 63) == 0) { sm.r1[t >> 6] = a1r; sm.r2[t >> 6] = a2r; }
    }
    __syncthreads();

    if (t < Dn) {
        const float S1 = sm.r1[0] + sm.r1[1];
        const float S2 = sm.r2[0] + sm.r2[1];
        const float m  = S1 * (1.0f / 128.0f);
        const float vr = S2 * (1.0f / 128.0f) - m * m;
        const float rs = rsqrtf(vr + 1e-5f);
        sm.x2[t] = silu_f((s - m) * rs * ng[t]);   // LN first, THEN silu
    }
    __syncthreads();

    // GEMV2: c in [ch*16, ch*16+16)
    {
        const int c0 = ch * 16;
        float q0 = 0.f, q1 = 0.f, q2 = 0.f, q3 = 0.f;
        #pragma unroll
        for (int c = 0; c < 16; ++c) {
            const float  xv = sm.x2[c0 + c];
            const float4 wv4 = *(const float4*)&nW2[(c0 + c) * Dn + og * 4];
            q0 += xv * wv4.x; q1 += xv * wv4.y; q2 += xv * wv4.z; q3 += xv * wv4.w;
        }
        *(float4*)&sm.pp[ch][og * 4] = make_float4(q0, q1, q2, q3);
    }
    __syncthreads();

    if (t < Dn) {
        float r = nb2[t];
        #pragma unroll
        for (int cc = 0; cc < 8; ++cc) r += sm.pp[cc][t];
        out[bi * Dn + t] = r;
    }
}

// ---------------------------------------------------------------------------
extern "C" void kernel_launch(void* const* d_in, const int* in_sizes, int n_in,
                              void* d_out, int out_size, void* d_ws, size_t ws_size,
                              hipStream_t stream)
{
    (void)in_sizes; (void)n_in; (void)out_size; (void)ws_size;

    const int*   atoms = (const int*)d_in[0];
    const float* rel   = (const float*)d_in[1];
    const int*   adj   = (const int*)d_in[2];
    const int*   mask  = (const int*)d_in[3];
    const float* soft  = (const float*)d_in[4];
    const float* atab  = (const float*)d_in[5];
    const float* ntab  = (const float*)d_in[6];
    const float* rW1   = (const float*)d_in[7];
    const float* rb1   = (const float*)d_in[8];
    const float* rg1   = (const float*)d_in[9];
    const float* rW2   = (const float*)d_in[10];
    const float* rb2   = (const float*)d_in[11];
    const float* rg2   = (const float*)d_in[12];
    const float* rW3   = (const float*)d_in[13];
    const float* rb3   = (const float*)d_in[14];
    const float* nW1   = (const float*)d_in[15];
    const float* nb1   = (const float*)d_in[16];
    const float* ng    = (const float*)d_in[17];
    const float* nW2   = (const float*)d_in[18];
    const float* nb2   = (const float*)d_in[19];

    __hip_bfloat16* table = (__hip_bfloat16*)d_ws;   // (TT+1) x 128 bf16 ~ 1 MB
    float* out = (float*)d_out;

    hipLaunchKernelGGL(k0_build_table, dim3(K0B), dim3(256), 0, stream,
                       rW1, rb1, rg1, rW2, rb2, rg2, rW3, rb3, table);
    hipLaunchKernelGGL(k1_fused, dim3(Bn * Nn), dim3(256), 0, stream,
                       atoms, rel, adj, mask, soft, ntab, table,
                       atab, nW1, nb1, ng, nW2, nb2, out);
}